// Round 10
// baseline (246.263 us; speedup 1.0000x reference)
//
#include <hip/hip_runtime.h>
#include <math.h>

#define B_ 2
#define S_ 2048
#define D_ 1024
#define H_ 16
#define E_ 64
#define Z_ (B_ * H_)
#define QBLK 128
#define NEG_BIG (-1e30f)

typedef short short8 __attribute__((ext_vector_type(8)));
typedef float f32x4 __attribute__((ext_vector_type(4)));

__device__ __forceinline__ ushort f2bf(float x) {  // RNE (epilogues)
    union { float f; unsigned u; } c; c.f = x;
    unsigned r = (c.u + 0x7FFFu + ((c.u >> 16) & 1u)) >> 16;
    return (ushort)r;
}
__device__ __forceinline__ ushort f2bf_fast(float x) {  // 2-op, hot loops
    union { float f; unsigned u; } c; c.f = x;
    return (ushort)((c.u + 0x8000u) >> 16);
}

__device__ __forceinline__ f32x4 mfma16(short8 a, short8 b, f32x4 c) {
    return __builtin_amdgcn_mfma_f32_16x16x32_bf16(a, b, c, 0, 0, 0);
}

// ---------------------------------------------------------------------------
// Streaming fp32 -> bf16 convert, 3 tensors in one launch. grid (4096, 3).
// ---------------------------------------------------------------------------
__global__ __launch_bounds__(256) void cvt3_kernel(
    const float* __restrict__ in0, const float* __restrict__ in1,
    const float* __restrict__ in2, ushort* __restrict__ out0,
    ushort* __restrict__ out1, ushort* __restrict__ out2, int n4) {
    const int which = blockIdx.y;
    const float* in = (which == 0) ? in0 : (which == 1) ? in1 : in2;
    ushort* out = (which == 0) ? out0 : (which == 1) ? out1 : out2;
    int i = blockIdx.x * 256 + threadIdx.x;
    if (i < n4) {
        float4 x = reinterpret_cast<const float4*>(in)[i];
        ushort4 p;
        p.x = f2bf(x.x); p.y = f2bf(x.y); p.z = f2bf(x.z); p.w = f2bf(x.w);
        reinterpret_cast<ushort4*>(out)[i] = p;
    }
}

// ---------------------------------------------------------------------------
// Weight prep (QKV): fp32 [K][N] slice -> bf16 [N][K].  grid (32, 2, 48).
// ---------------------------------------------------------------------------
__global__ __launch_bounds__(256) void wtrans3_kernel(
    const float* __restrict__ w0, const float* __restrict__ w1,
    const float* __restrict__ w2, ushort* __restrict__ o0,
    ushort* __restrict__ o1, ushort* __restrict__ o2) {
    __shared__ float tile[32][33];
    const int zz = blockIdx.z;
    const int which = zz >> 4, h = zz & 15;
    const float* in = (which == 0) ? w0 : (which == 1) ? w1 : w2;
    ushort* out = (which == 0) ? o0 : (which == 1) ? o1 : o2;
    const int K = D_, N = E_;
    const float* ins = in + (size_t)h * K * N;
    ushort* outs = out + (size_t)h * K * N;
    const int k0 = blockIdx.x * 32, n0 = blockIdx.y * 32;
    const int tx = threadIdx.x & 31, ty = threadIdx.x >> 5;
#pragma unroll
    for (int r = 0; r < 32; r += 8)
        tile[ty + r][tx] = ins[(size_t)(k0 + ty + r) * N + n0 + tx];
    __syncthreads();
#pragma unroll
    for (int r = 0; r < 32; r += 8)
        outs[(size_t)(n0 + ty + r) * K + k0 + tx] = f2bf(tile[tx][ty + r]);
}

// Wo prep: fp32 [K][N] -> bf16 [N][K], grid (32, 32).
__global__ __launch_bounds__(256) void wtrans_kernel(
    const float* __restrict__ in, ushort* __restrict__ out, int K, int N) {
    __shared__ float tile[32][33];
    const int k0 = blockIdx.x * 32, n0 = blockIdx.y * 32;
    const int tx = threadIdx.x & 31, ty = threadIdx.x >> 5;
#pragma unroll
    for (int r = 0; r < 32; r += 8)
        tile[ty + r][tx] = in[(size_t)(k0 + ty + r) * N + n0 + tx];
    __syncthreads();
#pragma unroll
    for (int r = 0; r < 32; r += 8)
        out[(size_t)(n0 + ty + r) * K + k0 + tx] = f2bf(tile[tx][ty + r]);
}

// ---------------------------------------------------------------------------
// Fused Q+K+V 128x128-tile bf16 MFMA projection.  grid 768 x 512 threads.
// which = bid>>8 (0:q->qh scaled, 1:k->kh, 2:v->vt transposed).
// Double-buffered LDS, register prefetch, 1 barrier per K-step.
// ---------------------------------------------------------------------------
__global__ __launch_bounds__(512) void proj3_mfma_kernel(
    const ushort* __restrict__ xq, const ushort* __restrict__ xk,
    const ushort* __restrict__ xv, const ushort* __restrict__ Wqt,
    const ushort* __restrict__ Wkt, const ushort* __restrict__ Wvt,
    const float* __restrict__ bq, const float* __restrict__ bk,
    const float* __restrict__ bv, ushort* __restrict__ qh,
    ushort* __restrict__ kh, ushort* __restrict__ vt, float qscale) {
    const int bid = blockIdx.x;
    const int which = bid >> 8;
    const int inner = bid & 255;
    const ushort* Xb = (which == 0) ? xq : (which == 1) ? xk : xv;
    const ushort* Wt = (which == 0) ? Wqt : (which == 1) ? Wkt : Wvt;
    const float* bias = (which == 0) ? bq : (which == 1) ? bk : bv;
    ushort* out = (which == 0) ? qh : (which == 1) ? kh : vt;
    const float oscale = (which == 0) ? qscale : 1.0f;

    const int w = (inner & 7) * 32 + (inner >> 3);  // XCD swizzle
    const int mt = w >> 3, nt = w & 7;
    const int gm0 = mt * 128, n0 = nt * 128;
    const int t = threadIdx.x;
    const int wv = t >> 6, l = t & 63, j = l & 15, g = l >> 4;
    const int wm = wv >> 2, wn = wv & 3;

    __shared__ int4 Xs[2][1024];  // [128 rows][8 blk] XOR-swizzled
    __shared__ int4 Ws[2][1024];

    const f32x4 zf = {0.f, 0.f, 0.f, 0.f};
    f32x4 acc[4][2];
#pragma unroll
    for (int mm = 0; mm < 4; ++mm) { acc[mm][0] = zf; acc[mm][1] = zf; }

    const int rr0 = t >> 3, bb0 = t & 7;
    const int rr1 = (t + 512) >> 3, bb1 = t & 7;
    const int slot0 = rr0 * 8 + (bb0 ^ (rr0 & 7));
    const int slot1 = rr1 * 8 + (bb1 ^ (rr1 & 7));

    Xs[0][slot0] = *reinterpret_cast<const int4*>(Xb + (size_t)(gm0 + rr0) * D_ + bb0 * 8);
    Ws[0][slot0] = *reinterpret_cast<const int4*>(Wt + (size_t)(n0 + rr0) * D_ + bb0 * 8);
    Xs[0][slot1] = *reinterpret_cast<const int4*>(Xb + (size_t)(gm0 + rr1) * D_ + bb1 * 8);
    Ws[0][slot1] = *reinterpret_cast<const int4*>(Wt + (size_t)(n0 + rr1) * D_ + bb1 * 8);
    __syncthreads();

    for (int ks = 0; ks < 16; ++ks) {
        const int cur = ks & 1;
        const bool pf = (ks < 15);
        int4 xr0, wr0, xr1, wr1;
        if (pf) {
            const int k0n = (ks + 1) * 64;
            xr0 = *reinterpret_cast<const int4*>(Xb + (size_t)(gm0 + rr0) * D_ + k0n + bb0 * 8);
            wr0 = *reinterpret_cast<const int4*>(Wt + (size_t)(n0 + rr0) * D_ + k0n + bb0 * 8);
            xr1 = *reinterpret_cast<const int4*>(Xb + (size_t)(gm0 + rr1) * D_ + k0n + bb1 * 8);
            wr1 = *reinterpret_cast<const int4*>(Wt + (size_t)(n0 + rr1) * D_ + k0n + bb1 * 8);
        }

        __builtin_amdgcn_s_setprio(1);
#pragma unroll
        for (int eh = 0; eh < 2; ++eh) {
            short8 bfr[2];
#pragma unroll
            for (int nn = 0; nn < 2; ++nn) {
                int e = wn * 32 + nn * 16 + j;
                bfr[nn] = *reinterpret_cast<const short8*>(
                    &Ws[cur][e * 8 + ((eh * 4 + g) ^ (e & 7))]);
            }
#pragma unroll
            for (int mm = 0; mm < 4; ++mm) {
                int arow = wm * 64 + mm * 16 + j;
                short8 a = *reinterpret_cast<const short8*>(
                    &Xs[cur][arow * 8 + ((eh * 4 + g) ^ (arow & 7))]);
                acc[mm][0] = mfma16(a, bfr[0], acc[mm][0]);
                acc[mm][1] = mfma16(a, bfr[1], acc[mm][1]);
            }
        }
        __builtin_amdgcn_s_setprio(0);

        if (pf) {
            Xs[cur ^ 1][slot0] = xr0; Ws[cur ^ 1][slot0] = wr0;
            Xs[cur ^ 1][slot1] = xr1; Ws[cur ^ 1][slot1] = wr1;
        }
        __syncthreads();
    }

#pragma unroll
    for (int nn = 0; nn < 2; ++nn) {
        const int ncol = n0 + wn * 32 + nn * 16 + j;
        const int h = ncol >> 6, col = ncol & 63;
        const float bvv = bias[ncol];
#pragma unroll
        for (int mm = 0; mm < 4; ++mm) {
            const int m = gm0 + wm * 64 + mm * 16 + g * 4;
            const int b = m >> 11, s = m & 2047;
            if (which != 2) {
#pragma unroll
                for (int r = 0; r < 4; ++r)
                    out[((size_t)(b * H_ + h) * S_ + s + r) * E_ + col] =
                        f2bf((acc[mm][nn][r] + bvv) * oscale);
            } else {
                ushort4 pk;
                pk.x = f2bf(acc[mm][nn][0] + bvv);
                pk.y = f2bf(acc[mm][nn][1] + bvv);
                pk.z = f2bf(acc[mm][nn][2] + bvv);
                pk.w = f2bf(acc[mm][nn][3] + bvv);
                *reinterpret_cast<ushort4*>(
                    &out[((size_t)(b * H_ + h) * E_ + col) * S_ + s]) = pk;
            }
        }
    }
}

// ---------------------------------------------------------------------------
// Fused attention, QBLK=128, 8 waves, two-pass no-max softmax (exp2 domain),
// double-buffered K/V reg-staging.  PAIR-BALANCED: each block handles q-tiles
// pr and 15-pr sequentially -> constant 68 tile-iters + constant zero-fill
// per block (kills the 1.8x CU-span imbalance of the 512-block version).
// grid 256 x 512 (XCD-swizzled: 4 z x 8 pairs per XCD).
// ---------------------------------------------------------------------------
__global__ __launch_bounds__(512) void attn_fused_kernel(
    const ushort* __restrict__ qh, const ushort* __restrict__ kh,
    const ushort* __restrict__ vt, float* __restrict__ wts,
    ushort* __restrict__ attnc) {
    const int f = blockIdx.x;
    const int xcd = f & 7, w = f >> 3;          // w in [0,32)
    const int z = xcd * 4 + (w >> 3);
    const int pr = w & 7;

    const int t = threadIdx.x;
    const int wv = t >> 6, l = t & 63, j = l & 15, g = l >> 4;

    const ushort* qhz = qh + (size_t)z * S_ * E_;
    const ushort* khz = kh + (size_t)z * S_ * E_;
    const ushort* vtz = vt + (size_t)z * E_ * S_;
    float* wz = wts + (size_t)z * S_ * S_;
    const int b = z >> 4, hh = z & 15;

    __shared__ int4 Kb[2][512];
    __shared__ int4 Vb[2][512];
    __shared__ __align__(16) ushort Ps[8][16][72];

    const int rr = t >> 3, bb = t & 7;
    const int lds_i = rr * 8 + (bb ^ (rr & 7));
    const int koff = rr * 64 + bb * 8;
    const int voff = rr * 2048 + bb * 8;

    const f32x4 zf = {0.f, 0.f, 0.f, 0.f};

    for (int half = 0; half < 2; ++half) {
        const int qt = half ? (15 - pr) : pr;
        const int q0 = qt * QBLK;
        const int ktmax = 2 * qt + 1;  // always odd: last LDS read is buf 1

        short8 qf[2];
        {
            const ushort* qrow = qhz + (size_t)(q0 + wv * 16 + j) * E_;
            qf[0] = *reinterpret_cast<const short8*>(qrow + g * 8);
            qf[1] = *reinterpret_cast<const short8*>(qrow + 32 + g * 8);
        }
        const int qr_base = q0 + wv * 16 + g * 4;  // + r

        float lsum[4] = {0.f, 0.f, 0.f, 0.f};

        // ---------------- phase 1: per-lane denominator (m = 0) ---------
        Kb[0][lds_i] = *reinterpret_cast<const int4*>(khz + koff);
        __syncthreads();
        for (int kt = 0; kt <= ktmax; ++kt) {
            const int cur = kt & 1;
            const bool pf = (kt < ktmax);
            int4 kreg;
            if (pf)
                kreg = *reinterpret_cast<const int4*>(khz + (kt + 1) * 4096 +
                                                      koff);

            f32x4 sacc[4];
#pragma unroll
            for (int n = 0; n < 4; ++n) sacc[n] = zf;
            __builtin_amdgcn_s_setprio(1);
#pragma unroll
            for (int eh = 0; eh < 2; ++eh) {
#pragma unroll
                for (int n = 0; n < 4; ++n) {
                    const int kc = n * 16 + j;
                    short8 kf = *reinterpret_cast<const short8*>(
                        &Kb[cur][kc * 8 + ((eh * 4 + g) ^ (j & 7))]);
                    sacc[n] = mfma16(qf[eh], kf, sacc[n]);
                }
            }
            __builtin_amdgcn_s_setprio(0);

            if (kt >= 2 * qt) {
#pragma unroll
                for (int n = 0; n < 4; ++n) {
                    const int col = kt * 64 + n * 16 + j;
#pragma unroll
                    for (int r = 0; r < 4; ++r)
                        if (col > qr_base + r) sacc[n][r] = NEG_BIG;
                }
            }
#pragma unroll
            for (int r = 0; r < 4; ++r)
                lsum[r] += (exp2f(sacc[0][r]) + exp2f(sacc[1][r])) +
                           (exp2f(sacc[2][r]) + exp2f(sacc[3][r]));

            if (pf) Kb[cur ^ 1][lds_i] = kreg;
            __syncthreads();
        }

        // one-time cross-lane merge (16 lanes j share a q-row)
        float invl[4];
#pragma unroll
        for (int r = 0; r < 4; ++r) {
            float tt = lsum[r];
            tt += __shfl_xor(tt, 1);
            tt += __shfl_xor(tt, 2);
            tt += __shfl_xor(tt, 4);
            tt += __shfl_xor(tt, 8);
            invl[r] = 1.0f / tt;
        }

        // ---------------- phase 2: recompute, write weights, PV ---------
        f32x4 oacc[4];
#pragma unroll
        for (int n = 0; n < 4; ++n) oacc[n] = zf;

        Kb[0][lds_i] = *reinterpret_cast<const int4*>(khz + koff);
        Vb[0][lds_i] = *reinterpret_cast<const int4*>(vtz + voff);
        __syncthreads();
        for (int kt = 0; kt <= ktmax; ++kt) {
            const int cur = kt & 1;
            const bool pf = (kt < ktmax);
            int4 kreg, vreg;
            if (pf) {
                kreg = *reinterpret_cast<const int4*>(khz + (kt + 1) * 4096 +
                                                      koff);
                vreg = *reinterpret_cast<const int4*>(vtz + (kt + 1) * 64 +
                                                      voff);
            }

            f32x4 sacc[4];
#pragma unroll
            for (int n = 0; n < 4; ++n) sacc[n] = zf;
            __builtin_amdgcn_s_setprio(1);
#pragma unroll
            for (int eh = 0; eh < 2; ++eh) {
#pragma unroll
                for (int n = 0; n < 4; ++n) {
                    const int kc = n * 16 + j;
                    short8 kf = *reinterpret_cast<const short8*>(
                        &Kb[cur][kc * 8 + ((eh * 4 + g) ^ (j & 7))]);
                    sacc[n] = mfma16(qf[eh], kf, sacc[n]);
                }
            }
            __builtin_amdgcn_s_setprio(0);

            if (kt >= 2 * qt) {
#pragma unroll
                for (int n = 0; n < 4; ++n) {
                    const int col = kt * 64 + n * 16 + j;
#pragma unroll
                    for (int r = 0; r < 4; ++r)
                        if (col > qr_base + r) sacc[n][r] = NEG_BIG;
                }
            }

#pragma unroll
            for (int n = 0; n < 4; ++n) {
#pragma unroll
                for (int r = 0; r < 4; ++r) {
                    float p = exp2f(sacc[n][r]) * invl[r];
                    wz[(size_t)(qr_base + r) * S_ + kt * 64 + n * 16 + j] = p;
                    Ps[wv][g * 4 + r][n * 16 + j] = f2bf_fast(p);
                }
            }

            __builtin_amdgcn_s_setprio(1);
#pragma unroll
            for (int ks = 0; ks < 2; ++ks) {
                short8 pa = *reinterpret_cast<const short8*>(
                    &Ps[wv][j][ks * 32 + g * 8]);
#pragma unroll
                for (int n = 0; n < 4; ++n) {
                    const int e = n * 16 + j;
                    short8 vb = *reinterpret_cast<const short8*>(
                        &Vb[cur][e * 8 + ((ks * 4 + g) ^ (j & 7))]);
                    oacc[n] = mfma16(pa, vb, oacc[n]);
                }
            }
            __builtin_amdgcn_s_setprio(0);

            if (pf) {
                Kb[cur ^ 1][lds_i] = kreg;
                Vb[cur ^ 1][lds_i] = vreg;
            }
            __syncthreads();
        }

        // write attn bf16 in concat layout [b][s][h*64+e]
#pragma unroll
        for (int n = 0; n < 4; ++n)
#pragma unroll
            for (int r = 0; r < 4; ++r)
                attnc[((size_t)(b * S_ + qr_base + r)) * D_ + hh * E_ +
                      n * 16 + j] = f2bf_fast(oacc[n][r]);

        // zero-fill the fully-masked (upper-triangle) weight columns
        const int c0 = q0 + QBLK;
        const int w4 = (S_ - c0) >> 2;
        if (w4 > 0) {
            const float4 z4 = make_float4(0.f, 0.f, 0.f, 0.f);
            for (int row = 0; row < QBLK; ++row) {
                float4* rp = reinterpret_cast<float4*>(
                    wz + (size_t)(q0 + row) * S_ + c0);
                for (int c = t; c < w4; c += 512) rp[c] = z4;
            }
        }
        // no extra barrier needed: next half's prologue writes Kb[0]/Vb[0],
        // whose last readers finished before this half's final loop barrier.
    }
}

// ---------------------------------------------------------------------------
// 128x128-tile out-projection: attnc bf16 [4096][1024] x Wot bf16 [n][k]
// + bo -> out fp32 [4096][1024].  grid 256 (XCD-swizzled), block 512.
// ---------------------------------------------------------------------------
__global__ __launch_bounds__(512) void outproj_mfma_kernel(
    const ushort* __restrict__ A, const ushort* __restrict__ Wot,
    const float* __restrict__ bo, float* __restrict__ out) {
    const int bid = blockIdx.x;
    const int w = (bid & 7) * 32 + (bid >> 3);
    const int mt = w >> 3, nt = w & 7;
    const int gm0 = mt * 128, n0 = nt * 128;
    const int t = threadIdx.x;
    const int wv = t >> 6, l = t & 63, j = l & 15, g = l >> 4;
    const int wm = wv >> 2, wn = wv & 3;

    __shared__ int4 As[2][1024];
    __shared__ int4 Bs[2][1024];

    const f32x4 zf = {0.f, 0.f, 0.f, 0.f};
    f32x4 acc[4][2];
#pragma unroll
    for (int mm = 0; mm < 4; ++mm) { acc[mm][0] = zf; acc[mm][1] = zf; }

    const int rr0 = t >> 3, bb0 = t & 7;
    const int rr1 = (t + 512) >> 3, bb1 = t & 7;
    const int slot0 = rr0 * 8 + (bb0 ^ (rr0 & 7));
    const int slot1 = rr1 * 8 + (bb1 ^ (rr1 & 7));

    As[0][slot0] = *reinterpret_cast<const int4*>(A + (size_t)(gm0 + rr0) * D_ + bb0 * 8);
    Bs[0][slot0] = *reinterpret_cast<const int4*>(Wot + (size_t)(n0 + rr0) * D_ + bb0 * 8);
    As[0][slot1] = *reinterpret_cast<const int4*>(A + (size_t)(gm0 + rr1) * D_ + bb1 * 8);
    Bs[0][slot1] = *reinterpret_cast<const int4*>(Wot + (size_t)(n0 + rr1) * D_ + bb1 * 8);
    __syncthreads();

    for (int ks = 0; ks < 16; ++ks) {
        const int cur = ks & 1;
        const bool pf = (ks < 15);
        int4 ar0, br0, ar1, br1;
        if (pf) {
            const int k0n = (ks + 1) * 64;
            ar0 = *reinterpret_cast<const int4*>(A + (size_t)(gm0 + rr0) * D_ + k0n + bb0 * 8);
            br0 = *reinterpret_cast<const int4*>(Wot + (size_t)(n0 + rr0) * D_ + k0n + bb0 * 8);
            ar1 = *reinterpret_cast<const int4*>(A + (size_t)(gm0 + rr1) * D_ + k0n + bb1 * 8);
            br1 = *reinterpret_cast<const int4*>(Wot + (size_t)(n0 + rr1) * D_ + k0n + bb1 * 8);
        }

        __builtin_amdgcn_s_setprio(1);
#pragma unroll
        for (int eh = 0; eh < 2; ++eh) {
            short8 bfr[2];
#pragma unroll
            for (int nn = 0; nn < 2; ++nn) {
                int e = wn * 32 + nn * 16 + j;
                bfr[nn] = *reinterpret_cast<const short8*>(
                    &Bs[cur][e * 8 + ((eh * 4 + g) ^ (e & 7))]);
            }
#pragma unroll
            for (int mm = 0; mm < 4; ++mm) {
                int arow = wm * 64 + mm * 16 + j;
                short8 a = *reinterpret_cast<const short8*>(
                    &As[cur][arow * 8 + ((eh * 4 + g) ^ (arow & 7))]);
                acc[mm][0] = mfma16(a, bfr[0], acc[mm][0]);
                acc[mm][1] = mfma16(a, bfr[1], acc[mm][1]);
            }
        }
        __builtin_amdgcn_s_setprio(0);

        if (pf) {
            As[cur ^ 1][slot0] = ar0; Bs[cur ^ 1][slot0] = br0;
            As[cur ^ 1][slot1] = ar1; Bs[cur ^ 1][slot1] = br1;
        }
        __syncthreads();
    }

#pragma unroll
    for (int nn = 0; nn < 2; ++nn) {
        const int ncol = n0 + wn * 32 + nn * 16 + j;
        const float bvv = bo[ncol];
#pragma unroll
        for (int mm = 0; mm < 4; ++mm) {
            const int m = gm0 + wm * 64 + mm * 16 + g * 4;
#pragma unroll
            for (int r = 0; r < 4; ++r)
                out[(size_t)(m + r) * D_ + ncol] = acc[mm][nn][r] + bvv;
        }
    }
}

// ---------------------------------------------------------------------------
extern "C" void kernel_launch(void* const* d_in, const int* in_sizes, int n_in,
                              void* d_out, int out_size, void* d_ws,
                              size_t ws_size, hipStream_t stream) {
    const float* q = (const float*)d_in[0];
    const float* k = (const float*)d_in[1];
    const float* v = (const float*)d_in[2];
    const float* Wq = (const float*)d_in[3];
    const float* bq = (const float*)d_in[4];
    const float* Wk = (const float*)d_in[5];
    const float* bk = (const float*)d_in[6];
    const float* Wv = (const float*)d_in[7];
    const float* bv = (const float*)d_in[8];
    const float* Wo = (const float*)d_in[9];
    const float* bo = (const float*)d_in[10];

    float* out = (float*)d_out;                    // [B,S,D]
    float* wts = out + (size_t)B_ * S_ * D_;       // [B,H,S,S]

    const size_t NZ = (size_t)Z_ * S_ * E_;        // 4,194,304
    const size_t NW = (size_t)H_ * E_ * D_;        // 1,048,576
    ushort* qh = (ushort*)d_ws;                    // bf16 [z][s][64] (scaled)
    ushort* kh = qh + NZ;                          // bf16 [z][s][64]
    ushort* vt = kh + NZ;                          // bf16 [z][64][s]
    ushort* attnc = vt + NZ;                       // bf16 [4096][1024] concat
    ushort* Wqt = attnc + NZ;                      // bf16 [h][64][1024]
    ushort* Wkt = Wqt + NW;
    ushort* Wvt = Wkt + NW;
    ushort* Wot = Wvt + NW;                        // bf16 [1024][1024] ([n][k])

    // bf16 copies of q/k/v staged in the (not-yet-written) wts region of
    // d_out; dead before attn_fused writes wts.
    ushort* xq = (ushort*)wts;
    ushort* xk = xq + NZ;
    ushort* xv = xk + NZ;

    const float QSCALE = 0.125f * 1.44269504088896340736f;  // 1/8 * log2(e)
    const int n4 = (int)(NZ / 4);

    dim3 b256(256), b512(512);
    cvt3_kernel<<<dim3(4096, 3), b256, 0, stream>>>(q, k, v, xq, xk, xv, n4);
    wtrans3_kernel<<<dim3(32, 2, 48), b256, 0, stream>>>(Wq, Wk, Wv, Wqt, Wkt,
                                                         Wvt);
    wtrans_kernel<<<dim3(32, 32, 1), b256, 0, stream>>>(Wo, Wot, D_, D_);
    proj3_mfma_kernel<<<dim3(768), b512, 0, stream>>>(
        xq, xk, xv, Wqt, Wkt, Wvt, bq, bk, bv, qh, kh, vt, QSCALE);
    attn_fused_kernel<<<dim3(256), b512, 0, stream>>>(qh, kh, vt, wts, attnc);
    outproj_mfma_kernel<<<dim3(256), b512, 0, stream>>>(attnc, Wot, bo, out);
}

// Round 11
// 234.128 us; speedup vs baseline: 1.0518x; 1.0518x over previous
//
#include <hip/hip_runtime.h>
#include <math.h>

#define B_ 2
#define S_ 2048
#define D_ 1024
#define H_ 16
#define E_ 64
#define Z_ (B_ * H_)
#define QBLK 128
#define NEG_BIG (-1e30f)

typedef short short8 __attribute__((ext_vector_type(8)));
typedef float f32x4 __attribute__((ext_vector_type(4)));

__device__ __forceinline__ ushort f2bf(float x) {  // RNE (epilogues)
    union { float f; unsigned u; } c; c.f = x;
    unsigned r = (c.u + 0x7FFFu + ((c.u >> 16) & 1u)) >> 16;
    return (ushort)r;
}
__device__ __forceinline__ ushort f2bf_fast(float x) {  // 2-op, hot loops
    union { float f; unsigned u; } c; c.f = x;
    return (ushort)((c.u + 0x8000u) >> 16);
}

__device__ __forceinline__ f32x4 mfma16(short8 a, short8 b, f32x4 c) {
    return __builtin_amdgcn_mfma_f32_16x16x32_bf16(a, b, c, 0, 0, 0);
}

// ---------------------------------------------------------------------------
// Streaming fp32 -> bf16 convert, 3 tensors in one launch. grid (4096, 3).
// ---------------------------------------------------------------------------
__global__ __launch_bounds__(256) void cvt3_kernel(
    const float* __restrict__ in0, const float* __restrict__ in1,
    const float* __restrict__ in2, ushort* __restrict__ out0,
    ushort* __restrict__ out1, ushort* __restrict__ out2, int n4) {
    const int which = blockIdx.y;
    const float* in = (which == 0) ? in0 : (which == 1) ? in1 : in2;
    ushort* out = (which == 0) ? out0 : (which == 1) ? out1 : out2;
    int i = blockIdx.x * 256 + threadIdx.x;
    if (i < n4) {
        float4 x = reinterpret_cast<const float4*>(in)[i];
        ushort4 p;
        p.x = f2bf(x.x); p.y = f2bf(x.y); p.z = f2bf(x.z); p.w = f2bf(x.w);
        reinterpret_cast<ushort4*>(out)[i] = p;
    }
}

// ---------------------------------------------------------------------------
// Weight prep (QKV): fp32 [K][N] slice -> bf16 [N][K].  grid (32, 2, 48).
// ---------------------------------------------------------------------------
__global__ __launch_bounds__(256) void wtrans3_kernel(
    const float* __restrict__ w0, const float* __restrict__ w1,
    const float* __restrict__ w2, ushort* __restrict__ o0,
    ushort* __restrict__ o1, ushort* __restrict__ o2) {
    __shared__ float tile[32][33];
    const int zz = blockIdx.z;
    const int which = zz >> 4, h = zz & 15;
    const float* in = (which == 0) ? w0 : (which == 1) ? w1 : w2;
    ushort* out = (which == 0) ? o0 : (which == 1) ? o1 : o2;
    const int K = D_, N = E_;
    const float* ins = in + (size_t)h * K * N;
    ushort* outs = out + (size_t)h * K * N;
    const int k0 = blockIdx.x * 32, n0 = blockIdx.y * 32;
    const int tx = threadIdx.x & 31, ty = threadIdx.x >> 5;
#pragma unroll
    for (int r = 0; r < 32; r += 8)
        tile[ty + r][tx] = ins[(size_t)(k0 + ty + r) * N + n0 + tx];
    __syncthreads();
#pragma unroll
    for (int r = 0; r < 32; r += 8)
        outs[(size_t)(n0 + ty + r) * K + k0 + tx] = f2bf(tile[tx][ty + r]);
}

// Wo prep: fp32 [K][N] -> bf16 [N][K], grid (32, 32).
__global__ __launch_bounds__(256) void wtrans_kernel(
    const float* __restrict__ in, ushort* __restrict__ out, int K, int N) {
    __shared__ float tile[32][33];
    const int k0 = blockIdx.x * 32, n0 = blockIdx.y * 32;
    const int tx = threadIdx.x & 31, ty = threadIdx.x >> 5;
#pragma unroll
    for (int r = 0; r < 32; r += 8)
        tile[ty + r][tx] = in[(size_t)(k0 + ty + r) * N + n0 + tx];
    __syncthreads();
#pragma unroll
    for (int r = 0; r < 32; r += 8)
        out[(size_t)(n0 + ty + r) * K + k0 + tx] = f2bf(tile[tx][ty + r]);
}

// ---------------------------------------------------------------------------
// Fused Q+K+V 128x128-tile bf16 MFMA projection.  grid 768 x 512 threads.
// which = bid>>8 (0:q->qh scaled, 1:k->kh, 2:v->vt transposed).
// Double-buffered LDS, register prefetch, 1 barrier per K-step.
// ---------------------------------------------------------------------------
__global__ __launch_bounds__(512) void proj3_mfma_kernel(
    const ushort* __restrict__ xq, const ushort* __restrict__ xk,
    const ushort* __restrict__ xv, const ushort* __restrict__ Wqt,
    const ushort* __restrict__ Wkt, const ushort* __restrict__ Wvt,
    const float* __restrict__ bq, const float* __restrict__ bk,
    const float* __restrict__ bv, ushort* __restrict__ qh,
    ushort* __restrict__ kh, ushort* __restrict__ vt, float qscale) {
    const int bid = blockIdx.x;
    const int which = bid >> 8;
    const int inner = bid & 255;
    const ushort* Xb = (which == 0) ? xq : (which == 1) ? xk : xv;
    const ushort* Wt = (which == 0) ? Wqt : (which == 1) ? Wkt : Wvt;
    const float* bias = (which == 0) ? bq : (which == 1) ? bk : bv;
    ushort* out = (which == 0) ? qh : (which == 1) ? kh : vt;
    const float oscale = (which == 0) ? qscale : 1.0f;

    const int w = (inner & 7) * 32 + (inner >> 3);  // XCD swizzle
    const int mt = w >> 3, nt = w & 7;
    const int gm0 = mt * 128, n0 = nt * 128;
    const int t = threadIdx.x;
    const int wv = t >> 6, l = t & 63, j = l & 15, g = l >> 4;
    const int wm = wv >> 2, wn = wv & 3;

    __shared__ int4 Xs[2][1024];  // [128 rows][8 blk] XOR-swizzled
    __shared__ int4 Ws[2][1024];

    const f32x4 zf = {0.f, 0.f, 0.f, 0.f};
    f32x4 acc[4][2];
#pragma unroll
    for (int mm = 0; mm < 4; ++mm) { acc[mm][0] = zf; acc[mm][1] = zf; }

    const int rr0 = t >> 3, bb0 = t & 7;
    const int rr1 = (t + 512) >> 3, bb1 = t & 7;
    const int slot0 = rr0 * 8 + (bb0 ^ (rr0 & 7));
    const int slot1 = rr1 * 8 + (bb1 ^ (rr1 & 7));

    Xs[0][slot0] = *reinterpret_cast<const int4*>(Xb + (size_t)(gm0 + rr0) * D_ + bb0 * 8);
    Ws[0][slot0] = *reinterpret_cast<const int4*>(Wt + (size_t)(n0 + rr0) * D_ + bb0 * 8);
    Xs[0][slot1] = *reinterpret_cast<const int4*>(Xb + (size_t)(gm0 + rr1) * D_ + bb1 * 8);
    Ws[0][slot1] = *reinterpret_cast<const int4*>(Wt + (size_t)(n0 + rr1) * D_ + bb1 * 8);
    __syncthreads();

    for (int ks = 0; ks < 16; ++ks) {
        const int cur = ks & 1;
        const bool pf = (ks < 15);
        int4 xr0, wr0, xr1, wr1;
        if (pf) {
            const int k0n = (ks + 1) * 64;
            xr0 = *reinterpret_cast<const int4*>(Xb + (size_t)(gm0 + rr0) * D_ + k0n + bb0 * 8);
            wr0 = *reinterpret_cast<const int4*>(Wt + (size_t)(n0 + rr0) * D_ + k0n + bb0 * 8);
            xr1 = *reinterpret_cast<const int4*>(Xb + (size_t)(gm0 + rr1) * D_ + k0n + bb1 * 8);
            wr1 = *reinterpret_cast<const int4*>(Wt + (size_t)(n0 + rr1) * D_ + k0n + bb1 * 8);
        }

        __builtin_amdgcn_s_setprio(1);
#pragma unroll
        for (int eh = 0; eh < 2; ++eh) {
            short8 bfr[2];
#pragma unroll
            for (int nn = 0; nn < 2; ++nn) {
                int e = wn * 32 + nn * 16 + j;
                bfr[nn] = *reinterpret_cast<const short8*>(
                    &Ws[cur][e * 8 + ((eh * 4 + g) ^ (e & 7))]);
            }
#pragma unroll
            for (int mm = 0; mm < 4; ++mm) {
                int arow = wm * 64 + mm * 16 + j;
                short8 a = *reinterpret_cast<const short8*>(
                    &Xs[cur][arow * 8 + ((eh * 4 + g) ^ (arow & 7))]);
                acc[mm][0] = mfma16(a, bfr[0], acc[mm][0]);
                acc[mm][1] = mfma16(a, bfr[1], acc[mm][1]);
            }
        }
        __builtin_amdgcn_s_setprio(0);

        if (pf) {
            Xs[cur ^ 1][slot0] = xr0; Ws[cur ^ 1][slot0] = wr0;
            Xs[cur ^ 1][slot1] = xr1; Ws[cur ^ 1][slot1] = wr1;
        }
        __syncthreads();
    }

#pragma unroll
    for (int nn = 0; nn < 2; ++nn) {
        const int ncol = n0 + wn * 32 + nn * 16 + j;
        const int h = ncol >> 6, col = ncol & 63;
        const float bvv = bias[ncol];
#pragma unroll
        for (int mm = 0; mm < 4; ++mm) {
            const int m = gm0 + wm * 64 + mm * 16 + g * 4;
            const int b = m >> 11, s = m & 2047;
            if (which != 2) {
#pragma unroll
                for (int r = 0; r < 4; ++r)
                    out[((size_t)(b * H_ + h) * S_ + s + r) * E_ + col] =
                        f2bf((acc[mm][nn][r] + bvv) * oscale);
            } else {
                ushort4 pk;
                pk.x = f2bf(acc[mm][nn][0] + bvv);
                pk.y = f2bf(acc[mm][nn][1] + bvv);
                pk.z = f2bf(acc[mm][nn][2] + bvv);
                pk.w = f2bf(acc[mm][nn][3] + bvv);
                *reinterpret_cast<ushort4*>(
                    &out[((size_t)(b * H_ + h) * E_ + col) * S_ + s]) = pk;
            }
        }
    }
}

// ---------------------------------------------------------------------------
// Fused attention, QBLK=128, 8 waves, two-pass no-max softmax (exp2 domain),
// double-buffered K/V reg-staging.  grid 512 x 512 (XCD-swizzled).
// CO-RESIDENT BALANCE: CU c holds blocks w=c and w=c+32; mapping gives them
// complementary qt (sum 15) so per-CU work is constant 68 tile-iters while
// keeping 2 blocks/CU overlap (R10's sequential pairing lost the overlap).
// ---------------------------------------------------------------------------
__global__ __launch_bounds__(512) void attn_fused_kernel(
    const ushort* __restrict__ qh, const ushort* __restrict__ kh,
    const ushort* __restrict__ vt, float* __restrict__ wts,
    ushort* __restrict__ attnc) {
    const int f = blockIdx.x;
    const int xcd = f & 7, w = f >> 3;          // w in [0,64)
    const int half = w >> 5, wl = w & 31;
    const int z = xcd * 4 + half * 2 + (wl >> 4);
    const int qm = wl & 15;
    const int qt = half ? (15 - qm) : qm;
    const int q0 = qt * QBLK;
    const int ktmax = 2 * qt + 1;

    const int t = threadIdx.x;
    const int wv = t >> 6, l = t & 63, j = l & 15, g = l >> 4;

    const ushort* qhz = qh + (size_t)z * S_ * E_;
    const ushort* khz = kh + (size_t)z * S_ * E_;
    const ushort* vtz = vt + (size_t)z * E_ * S_;
    float* wz = wts + (size_t)z * S_ * S_;

    __shared__ int4 Kb[2][512];
    __shared__ int4 Vb[2][512];
    __shared__ __align__(16) ushort Ps[8][16][72];

    const int rr = t >> 3, bb = t & 7;
    const int lds_i = rr * 8 + (bb ^ (rr & 7));
    const int koff = rr * 64 + bb * 8;
    const int voff = rr * 2048 + bb * 8;

    short8 qf[2];
    {
        const ushort* qrow = qhz + (size_t)(q0 + wv * 16 + j) * E_;
        qf[0] = *reinterpret_cast<const short8*>(qrow + g * 8);
        qf[1] = *reinterpret_cast<const short8*>(qrow + 32 + g * 8);
    }
    const int qr_base = q0 + wv * 16 + g * 4;  // + r

    const f32x4 zf = {0.f, 0.f, 0.f, 0.f};
    float lsum[4] = {0.f, 0.f, 0.f, 0.f};

    // ---------------- phase 1: per-lane denominator (m = 0) -------------
    Kb[0][lds_i] = *reinterpret_cast<const int4*>(khz + koff);
    __syncthreads();
    for (int kt = 0; kt <= ktmax; ++kt) {
        const int cur = kt & 1;
        const bool pf = (kt < ktmax);
        int4 kreg;
        if (pf)
            kreg = *reinterpret_cast<const int4*>(khz + (kt + 1) * 4096 + koff);

        f32x4 sacc[4];
#pragma unroll
        for (int n = 0; n < 4; ++n) sacc[n] = zf;
        __builtin_amdgcn_s_setprio(1);
#pragma unroll
        for (int eh = 0; eh < 2; ++eh) {
#pragma unroll
            for (int n = 0; n < 4; ++n) {
                const int kc = n * 16 + j;
                short8 kf = *reinterpret_cast<const short8*>(
                    &Kb[cur][kc * 8 + ((eh * 4 + g) ^ (j & 7))]);
                sacc[n] = mfma16(qf[eh], kf, sacc[n]);
            }
        }
        __builtin_amdgcn_s_setprio(0);

        if (kt >= 2 * qt) {
#pragma unroll
            for (int n = 0; n < 4; ++n) {
                const int col = kt * 64 + n * 16 + j;
#pragma unroll
                for (int r = 0; r < 4; ++r)
                    if (col > qr_base + r) sacc[n][r] = NEG_BIG;
            }
        }
#pragma unroll
        for (int r = 0; r < 4; ++r)
            lsum[r] += (exp2f(sacc[0][r]) + exp2f(sacc[1][r])) +
                       (exp2f(sacc[2][r]) + exp2f(sacc[3][r]));

        if (pf) Kb[cur ^ 1][lds_i] = kreg;
        __syncthreads();
    }

    // one-time cross-lane merge (16 lanes j share a q-row)
    float invl[4];
#pragma unroll
    for (int r = 0; r < 4; ++r) {
        float tt = lsum[r];
        tt += __shfl_xor(tt, 1);
        tt += __shfl_xor(tt, 2);
        tt += __shfl_xor(tt, 4);
        tt += __shfl_xor(tt, 8);
        invl[r] = 1.0f / tt;
    }

    // ---------------- phase 2: recompute, write weights, PV -------------
    f32x4 oacc[4];
#pragma unroll
    for (int n = 0; n < 4; ++n) oacc[n] = zf;

    Kb[0][lds_i] = *reinterpret_cast<const int4*>(khz + koff);
    Vb[0][lds_i] = *reinterpret_cast<const int4*>(vtz + voff);
    __syncthreads();
    for (int kt = 0; kt <= ktmax; ++kt) {
        const int cur = kt & 1;
        const bool pf = (kt < ktmax);
        int4 kreg, vreg;
        if (pf) {
            kreg = *reinterpret_cast<const int4*>(khz + (kt + 1) * 4096 + koff);
            vreg = *reinterpret_cast<const int4*>(vtz + (kt + 1) * 64 + voff);
        }

        f32x4 sacc[4];
#pragma unroll
        for (int n = 0; n < 4; ++n) sacc[n] = zf;
        __builtin_amdgcn_s_setprio(1);
#pragma unroll
        for (int eh = 0; eh < 2; ++eh) {
#pragma unroll
            for (int n = 0; n < 4; ++n) {
                const int kc = n * 16 + j;
                short8 kf = *reinterpret_cast<const short8*>(
                    &Kb[cur][kc * 8 + ((eh * 4 + g) ^ (j & 7))]);
                sacc[n] = mfma16(qf[eh], kf, sacc[n]);
            }
        }
        __builtin_amdgcn_s_setprio(0);

        if (kt >= 2 * qt) {
#pragma unroll
            for (int n = 0; n < 4; ++n) {
                const int col = kt * 64 + n * 16 + j;
#pragma unroll
                for (int r = 0; r < 4; ++r)
                    if (col > qr_base + r) sacc[n][r] = NEG_BIG;
            }
        }

#pragma unroll
        for (int n = 0; n < 4; ++n) {
#pragma unroll
            for (int r = 0; r < 4; ++r) {
                float p = exp2f(sacc[n][r]) * invl[r];
                wz[(size_t)(qr_base + r) * S_ + kt * 64 + n * 16 + j] = p;
                Ps[wv][g * 4 + r][n * 16 + j] = f2bf_fast(p);
            }
        }

        __builtin_amdgcn_s_setprio(1);
#pragma unroll
        for (int ks = 0; ks < 2; ++ks) {
            short8 pa =
                *reinterpret_cast<const short8*>(&Ps[wv][j][ks * 32 + g * 8]);
#pragma unroll
            for (int n = 0; n < 4; ++n) {
                const int e = n * 16 + j;
                short8 vb = *reinterpret_cast<const short8*>(
                    &Vb[cur][e * 8 + ((ks * 4 + g) ^ (j & 7))]);
                oacc[n] = mfma16(pa, vb, oacc[n]);
            }
        }
        __builtin_amdgcn_s_setprio(0);

        if (pf) {
            Kb[cur ^ 1][lds_i] = kreg;
            Vb[cur ^ 1][lds_i] = vreg;
        }
        __syncthreads();
    }

    // write attn bf16 in concat layout [b][s][h*64+e]
    {
        const int b = z >> 4, hh = z & 15;
#pragma unroll
        for (int n = 0; n < 4; ++n)
#pragma unroll
            for (int r = 0; r < 4; ++r)
                attnc[((size_t)(b * S_ + qr_base + r)) * D_ + hh * E_ +
                      n * 16 + j] = f2bf_fast(oacc[n][r]);
    }

    // zero-fill the fully-masked (upper-triangle) weight columns
    const int c0 = q0 + QBLK;
    const int w4 = (S_ - c0) >> 2;
    if (w4 > 0) {
        const float4 z4 = make_float4(0.f, 0.f, 0.f, 0.f);
        for (int row = 0; row < QBLK; ++row) {
            float4* rp =
                reinterpret_cast<float4*>(wz + (size_t)(q0 + row) * S_ + c0);
            for (int c = t; c < w4; c += 512) rp[c] = z4;
        }
    }
}

// ---------------------------------------------------------------------------
// 128x128-tile out-projection: attnc bf16 [4096][1024] x Wot bf16 [n][k]
// + bo -> out fp32 [4096][1024].  grid 256 (XCD-swizzled), block 512.
// ---------------------------------------------------------------------------
__global__ __launch_bounds__(512) void outproj_mfma_kernel(
    const ushort* __restrict__ A, const ushort* __restrict__ Wot,
    const float* __restrict__ bo, float* __restrict__ out) {
    const int bid = blockIdx.x;
    const int w = (bid & 7) * 32 + (bid >> 3);
    const int mt = w >> 3, nt = w & 7;
    const int gm0 = mt * 128, n0 = nt * 128;
    const int t = threadIdx.x;
    const int wv = t >> 6, l = t & 63, j = l & 15, g = l >> 4;
    const int wm = wv >> 2, wn = wv & 3;

    __shared__ int4 As[2][1024];
    __shared__ int4 Bs[2][1024];

    const f32x4 zf = {0.f, 0.f, 0.f, 0.f};
    f32x4 acc[4][2];
#pragma unroll
    for (int mm = 0; mm < 4; ++mm) { acc[mm][0] = zf; acc[mm][1] = zf; }

    const int rr0 = t >> 3, bb0 = t & 7;
    const int rr1 = (t + 512) >> 3, bb1 = t & 7;
    const int slot0 = rr0 * 8 + (bb0 ^ (rr0 & 7));
    const int slot1 = rr1 * 8 + (bb1 ^ (rr1 & 7));

    As[0][slot0] = *reinterpret_cast<const int4*>(A + (size_t)(gm0 + rr0) * D_ + bb0 * 8);
    Bs[0][slot0] = *reinterpret_cast<const int4*>(Wot + (size_t)(n0 + rr0) * D_ + bb0 * 8);
    As[0][slot1] = *reinterpret_cast<const int4*>(A + (size_t)(gm0 + rr1) * D_ + bb1 * 8);
    Bs[0][slot1] = *reinterpret_cast<const int4*>(Wot + (size_t)(n0 + rr1) * D_ + bb1 * 8);
    __syncthreads();

    for (int ks = 0; ks < 16; ++ks) {
        const int cur = ks & 1;
        const bool pf = (ks < 15);
        int4 ar0, br0, ar1, br1;
        if (pf) {
            const int k0n = (ks + 1) * 64;
            ar0 = *reinterpret_cast<const int4*>(A + (size_t)(gm0 + rr0) * D_ + k0n + bb0 * 8);
            br0 = *reinterpret_cast<const int4*>(Wot + (size_t)(n0 + rr0) * D_ + k0n + bb0 * 8);
            ar1 = *reinterpret_cast<const int4*>(A + (size_t)(gm0 + rr1) * D_ + k0n + bb1 * 8);
            br1 = *reinterpret_cast<const int4*>(Wot + (size_t)(n0 + rr1) * D_ + k0n + bb1 * 8);
        }

        __builtin_amdgcn_s_setprio(1);
#pragma unroll
        for (int eh = 0; eh < 2; ++eh) {
            short8 bfr[2];
#pragma unroll
            for (int nn = 0; nn < 2; ++nn) {
                int e = wn * 32 + nn * 16 + j;
                bfr[nn] = *reinterpret_cast<const short8*>(
                    &Bs[cur][e * 8 + ((eh * 4 + g) ^ (e & 7))]);
            }
#pragma unroll
            for (int mm = 0; mm < 4; ++mm) {
                int arow = wm * 64 + mm * 16 + j;
                short8 a = *reinterpret_cast<const short8*>(
                    &As[cur][arow * 8 + ((eh * 4 + g) ^ (arow & 7))]);
                acc[mm][0] = mfma16(a, bfr[0], acc[mm][0]);
                acc[mm][1] = mfma16(a, bfr[1], acc[mm][1]);
            }
        }
        __builtin_amdgcn_s_setprio(0);

        if (pf) {
            As[cur ^ 1][slot0] = ar0; Bs[cur ^ 1][slot0] = br0;
            As[cur ^ 1][slot1] = ar1; Bs[cur ^ 1][slot1] = br1;
        }
        __syncthreads();
    }

#pragma unroll
    for (int nn = 0; nn < 2; ++nn) {
        const int ncol = n0 + wn * 32 + nn * 16 + j;
        const float bvv = bo[ncol];
#pragma unroll
        for (int mm = 0; mm < 4; ++mm) {
            const int m = gm0 + wm * 64 + mm * 16 + g * 4;
#pragma unroll
            for (int r = 0; r < 4; ++r)
                out[(size_t)(m + r) * D_ + ncol] = acc[mm][nn][r] + bvv;
        }
    }
}

// ---------------------------------------------------------------------------
extern "C" void kernel_launch(void* const* d_in, const int* in_sizes, int n_in,
                              void* d_out, int out_size, void* d_ws,
                              size_t ws_size, hipStream_t stream) {
    const float* q = (const float*)d_in[0];
    const float* k = (const float*)d_in[1];
    const float* v = (const float*)d_in[2];
    const float* Wq = (const float*)d_in[3];
    const float* bq = (const float*)d_in[4];
    const float* Wk = (const float*)d_in[5];
    const float* bk = (const float*)d_in[6];
    const float* Wv = (const float*)d_in[7];
    const float* bv = (const float*)d_in[8];
    const float* Wo = (const float*)d_in[9];
    const float* bo = (const float*)d_in[10];

    float* out = (float*)d_out;                    // [B,S,D]
    float* wts = out + (size_t)B_ * S_ * D_;       // [B,H,S,S]

    const size_t NZ = (size_t)Z_ * S_ * E_;        // 4,194,304
    const size_t NW = (size_t)H_ * E_ * D_;        // 1,048,576
    ushort* qh = (ushort*)d_ws;                    // bf16 [z][s][64] (scaled)
    ushort* kh = qh + NZ;                          // bf16 [z][s][64]
    ushort* vt = kh + NZ;                          // bf16 [z][64][s]
    ushort* attnc = vt + NZ;                       // bf16 [4096][1024] concat
    ushort* Wqt = attnc + NZ;                      // bf16 [h][64][1024]
    ushort* Wkt = Wqt + NW;
    ushort* Wvt = Wkt + NW;
    ushort* Wot = Wvt + NW;                        // bf16 [1024][1024] ([n][k])

    // bf16 copies of q/k/v staged in the (not-yet-written) wts region of
    // d_out; dead before attn_fused writes wts.
    ushort* xq = (ushort*)wts;
    ushort* xk = xq + NZ;
    ushort* xv = xk + NZ;

    const float QSCALE = 0.125f * 1.44269504088896340736f;  // 1/8 * log2(e)
    const int n4 = (int)(NZ / 4);

    dim3 b256(256), b512(512);
    cvt3_kernel<<<dim3(4096, 3), b256, 0, stream>>>(q, k, v, xq, xk, xv, n4);
    wtrans3_kernel<<<dim3(32, 2, 48), b256, 0, stream>>>(Wq, Wk, Wv, Wqt, Wkt,
                                                         Wvt);
    wtrans_kernel<<<dim3(32, 32, 1), b256, 0, stream>>>(Wo, Wot, D_, D_);
    proj3_mfma_kernel<<<dim3(768), b512, 0, stream>>>(
        xq, xk, xv, Wqt, Wkt, Wvt, bq, bk, bv, qh, kh, vt, QSCALE);
    attn_fused_kernel<<<dim3(512), b512, 0, stream>>>(qh, kh, vt, wts, attnc);
    outproj_mfma_kernel<<<dim3(256), b512, 0, stream>>>(attnc, Wot, bo, out);
}

// Round 12
// 233.013 us; speedup vs baseline: 1.0569x; 1.0048x over previous
//
#include <hip/hip_runtime.h>
#include <math.h>

#define B_ 2
#define S_ 2048
#define D_ 1024
#define H_ 16
#define E_ 64
#define Z_ (B_ * H_)
#define QBLK 128
#define NEG_BIG (-1e30f)

typedef short short8 __attribute__((ext_vector_type(8)));
typedef float f32x4 __attribute__((ext_vector_type(4)));

__device__ __forceinline__ ushort f2bf(float x) {  // RNE (epilogues)
    union { float f; unsigned u; } c; c.f = x;
    unsigned r = (c.u + 0x7FFFu + ((c.u >> 16) & 1u)) >> 16;
    return (ushort)r;
}
__device__ __forceinline__ ushort f2bf_fast(float x) {  // 2-op, hot loops
    union { float f; unsigned u; } c; c.f = x;
    return (ushort)((c.u + 0x8000u) >> 16);
}

__device__ __forceinline__ f32x4 mfma16(short8 a, short8 b, f32x4 c) {
    return __builtin_amdgcn_mfma_f32_16x16x32_bf16(a, b, c, 0, 0, 0);
}

// ---------------------------------------------------------------------------
// Streaming fp32 -> bf16 convert, 3 tensors in one launch. grid (4096, 3).
// ---------------------------------------------------------------------------
__global__ __launch_bounds__(256) void cvt3_kernel(
    const float* __restrict__ in0, const float* __restrict__ in1,
    const float* __restrict__ in2, ushort* __restrict__ out0,
    ushort* __restrict__ out1, ushort* __restrict__ out2, int n4) {
    const int which = blockIdx.y;
    const float* in = (which == 0) ? in0 : (which == 1) ? in1 : in2;
    ushort* out = (which == 0) ? out0 : (which == 1) ? out1 : out2;
    int i = blockIdx.x * 256 + threadIdx.x;
    if (i < n4) {
        float4 x = reinterpret_cast<const float4*>(in)[i];
        ushort4 p;
        p.x = f2bf(x.x); p.y = f2bf(x.y); p.z = f2bf(x.z); p.w = f2bf(x.w);
        reinterpret_cast<ushort4*>(out)[i] = p;
    }
}

// ---------------------------------------------------------------------------
// Weight prep (QKV): fp32 [K][N] slice -> bf16 [N][K].  grid (32, 2, 48).
// ---------------------------------------------------------------------------
__global__ __launch_bounds__(256) void wtrans3_kernel(
    const float* __restrict__ w0, const float* __restrict__ w1,
    const float* __restrict__ w2, ushort* __restrict__ o0,
    ushort* __restrict__ o1, ushort* __restrict__ o2) {
    __shared__ float tile[32][33];
    const int zz = blockIdx.z;
    const int which = zz >> 4, h = zz & 15;
    const float* in = (which == 0) ? w0 : (which == 1) ? w1 : w2;
    ushort* out = (which == 0) ? o0 : (which == 1) ? o1 : o2;
    const int K = D_, N = E_;
    const float* ins = in + (size_t)h * K * N;
    ushort* outs = out + (size_t)h * K * N;
    const int k0 = blockIdx.x * 32, n0 = blockIdx.y * 32;
    const int tx = threadIdx.x & 31, ty = threadIdx.x >> 5;
#pragma unroll
    for (int r = 0; r < 32; r += 8)
        tile[ty + r][tx] = ins[(size_t)(k0 + ty + r) * N + n0 + tx];
    __syncthreads();
#pragma unroll
    for (int r = 0; r < 32; r += 8)
        outs[(size_t)(n0 + ty + r) * K + k0 + tx] = f2bf(tile[tx][ty + r]);
}

// Wo prep: fp32 [K][N] -> bf16 [N][K], grid (32, 32).
__global__ __launch_bounds__(256) void wtrans_kernel(
    const float* __restrict__ in, ushort* __restrict__ out, int K, int N) {
    __shared__ float tile[32][33];
    const int k0 = blockIdx.x * 32, n0 = blockIdx.y * 32;
    const int tx = threadIdx.x & 31, ty = threadIdx.x >> 5;
#pragma unroll
    for (int r = 0; r < 32; r += 8)
        tile[ty + r][tx] = in[(size_t)(k0 + ty + r) * N + n0 + tx];
    __syncthreads();
#pragma unroll
    for (int r = 0; r < 32; r += 8)
        out[(size_t)(n0 + ty + r) * K + k0 + tx] = f2bf(tile[tx][ty + r]);
}

// ---------------------------------------------------------------------------
// Fused Q+K+V 128x128-tile bf16 MFMA projection.  grid 768 x 512 threads.
// which = bid>>8 (0:q->qh scaled, 1:k->kh, 2:v->vt transposed).
// Double-buffered LDS, register prefetch, 1 barrier per K-step.
// ---------------------------------------------------------------------------
__global__ __launch_bounds__(512) void proj3_mfma_kernel(
    const ushort* __restrict__ xq, const ushort* __restrict__ xk,
    const ushort* __restrict__ xv, const ushort* __restrict__ Wqt,
    const ushort* __restrict__ Wkt, const ushort* __restrict__ Wvt,
    const float* __restrict__ bq, const float* __restrict__ bk,
    const float* __restrict__ bv, ushort* __restrict__ qh,
    ushort* __restrict__ kh, ushort* __restrict__ vt, float qscale) {
    const int bid = blockIdx.x;
    const int which = bid >> 8;
    const int inner = bid & 255;
    const ushort* Xb = (which == 0) ? xq : (which == 1) ? xk : xv;
    const ushort* Wt = (which == 0) ? Wqt : (which == 1) ? Wkt : Wvt;
    const float* bias = (which == 0) ? bq : (which == 1) ? bk : bv;
    ushort* out = (which == 0) ? qh : (which == 1) ? kh : vt;
    const float oscale = (which == 0) ? qscale : 1.0f;

    const int w = (inner & 7) * 32 + (inner >> 3);  // XCD swizzle
    const int mt = w >> 3, nt = w & 7;
    const int gm0 = mt * 128, n0 = nt * 128;
    const int t = threadIdx.x;
    const int wv = t >> 6, l = t & 63, j = l & 15, g = l >> 4;
    const int wm = wv >> 2, wn = wv & 3;

    __shared__ int4 Xs[2][1024];  // [128 rows][8 blk] XOR-swizzled
    __shared__ int4 Ws[2][1024];

    const f32x4 zf = {0.f, 0.f, 0.f, 0.f};
    f32x4 acc[4][2];
#pragma unroll
    for (int mm = 0; mm < 4; ++mm) { acc[mm][0] = zf; acc[mm][1] = zf; }

    const int rr0 = t >> 3, bb0 = t & 7;
    const int rr1 = (t + 512) >> 3, bb1 = t & 7;
    const int slot0 = rr0 * 8 + (bb0 ^ (rr0 & 7));
    const int slot1 = rr1 * 8 + (bb1 ^ (rr1 & 7));

    Xs[0][slot0] = *reinterpret_cast<const int4*>(Xb + (size_t)(gm0 + rr0) * D_ + bb0 * 8);
    Ws[0][slot0] = *reinterpret_cast<const int4*>(Wt + (size_t)(n0 + rr0) * D_ + bb0 * 8);
    Xs[0][slot1] = *reinterpret_cast<const int4*>(Xb + (size_t)(gm0 + rr1) * D_ + bb1 * 8);
    Ws[0][slot1] = *reinterpret_cast<const int4*>(Wt + (size_t)(n0 + rr1) * D_ + bb1 * 8);
    __syncthreads();

    for (int ks = 0; ks < 16; ++ks) {
        const int cur = ks & 1;
        const bool pf = (ks < 15);
        int4 xr0, wr0, xr1, wr1;
        if (pf) {
            const int k0n = (ks + 1) * 64;
            xr0 = *reinterpret_cast<const int4*>(Xb + (size_t)(gm0 + rr0) * D_ + k0n + bb0 * 8);
            wr0 = *reinterpret_cast<const int4*>(Wt + (size_t)(n0 + rr0) * D_ + k0n + bb0 * 8);
            xr1 = *reinterpret_cast<const int4*>(Xb + (size_t)(gm0 + rr1) * D_ + k0n + bb1 * 8);
            wr1 = *reinterpret_cast<const int4*>(Wt + (size_t)(n0 + rr1) * D_ + k0n + bb1 * 8);
        }

        __builtin_amdgcn_s_setprio(1);
#pragma unroll
        for (int eh = 0; eh < 2; ++eh) {
            short8 bfr[2];
#pragma unroll
            for (int nn = 0; nn < 2; ++nn) {
                int e = wn * 32 + nn * 16 + j;
                bfr[nn] = *reinterpret_cast<const short8*>(
                    &Ws[cur][e * 8 + ((eh * 4 + g) ^ (e & 7))]);
            }
#pragma unroll
            for (int mm = 0; mm < 4; ++mm) {
                int arow = wm * 64 + mm * 16 + j;
                short8 a = *reinterpret_cast<const short8*>(
                    &Xs[cur][arow * 8 + ((eh * 4 + g) ^ (arow & 7))]);
                acc[mm][0] = mfma16(a, bfr[0], acc[mm][0]);
                acc[mm][1] = mfma16(a, bfr[1], acc[mm][1]);
            }
        }
        __builtin_amdgcn_s_setprio(0);

        if (pf) {
            Xs[cur ^ 1][slot0] = xr0; Ws[cur ^ 1][slot0] = wr0;
            Xs[cur ^ 1][slot1] = xr1; Ws[cur ^ 1][slot1] = wr1;
        }
        __syncthreads();
    }

#pragma unroll
    for (int nn = 0; nn < 2; ++nn) {
        const int ncol = n0 + wn * 32 + nn * 16 + j;
        const int h = ncol >> 6, col = ncol & 63;
        const float bvv = bias[ncol];
#pragma unroll
        for (int mm = 0; mm < 4; ++mm) {
            const int m = gm0 + wm * 64 + mm * 16 + g * 4;
            const int b = m >> 11, s = m & 2047;
            if (which != 2) {
#pragma unroll
                for (int r = 0; r < 4; ++r)
                    out[((size_t)(b * H_ + h) * S_ + s + r) * E_ + col] =
                        f2bf((acc[mm][nn][r] + bvv) * oscale);
            } else {
                ushort4 pk;
                pk.x = f2bf(acc[mm][nn][0] + bvv);
                pk.y = f2bf(acc[mm][nn][1] + bvv);
                pk.z = f2bf(acc[mm][nn][2] + bvv);
                pk.w = f2bf(acc[mm][nn][3] + bvv);
                *reinterpret_cast<ushort4*>(
                    &out[((size_t)(b * H_ + h) * E_ + col) * S_ + s]) = pk;
            }
        }
    }
}

// ---------------------------------------------------------------------------
// Fused attention, QBLK=128, 8 waves, two-pass no-max softmax (exp2 domain).
// Phase 2 is 1-deep PV-pipelined (T15): PV(kt-1) overlaps exp/stores of kt
// on separate pipes.  V triple-buffered so the single barrier/iter stays
// race-free; Ps double-buffered (per-wave, no cross-wave sharing).
// grid 512 x 512 (XCD-swizzled, complementary-qt mapping).
// ---------------------------------------------------------------------------
__global__ __launch_bounds__(512) void attn_fused_kernel(
    const ushort* __restrict__ qh, const ushort* __restrict__ kh,
    const ushort* __restrict__ vt, float* __restrict__ wts,
    ushort* __restrict__ attnc) {
    const int f = blockIdx.x;
    const int xcd = f & 7, w = f >> 3;          // w in [0,64)
    const int half = w >> 5, wl = w & 31;
    const int z = xcd * 4 + half * 2 + (wl >> 4);
    const int qm = wl & 15;
    const int qt = half ? (15 - qm) : qm;
    const int q0 = qt * QBLK;
    const int ktmax = 2 * qt + 1;

    const int t = threadIdx.x;
    const int wv = t >> 6, l = t & 63, j = l & 15, g = l >> 4;

    const ushort* qhz = qh + (size_t)z * S_ * E_;
    const ushort* khz = kh + (size_t)z * S_ * E_;
    const ushort* vtz = vt + (size_t)z * E_ * S_;
    float* wz = wts + (size_t)z * S_ * S_;

    __shared__ int4 Kb[2][512];                       // 16 KB
    __shared__ int4 Vb[3][512];                       // 24 KB (triple buffer)
    __shared__ __align__(16) ushort Ps[2][8][16][72]; // 36 KB (2-deep P)

    const int rr = t >> 3, bb = t & 7;
    const int lds_i = rr * 8 + (bb ^ (rr & 7));
    const int koff = rr * 64 + bb * 8;
    const int voff = rr * 2048 + bb * 8;

    short8 qf[2];
    {
        const ushort* qrow = qhz + (size_t)(q0 + wv * 16 + j) * E_;
        qf[0] = *reinterpret_cast<const short8*>(qrow + g * 8);
        qf[1] = *reinterpret_cast<const short8*>(qrow + 32 + g * 8);
    }
    const int qr_base = q0 + wv * 16 + g * 4;  // + r

    const f32x4 zf = {0.f, 0.f, 0.f, 0.f};
    float lsum[4] = {0.f, 0.f, 0.f, 0.f};

    // ---------------- phase 1: per-lane denominator (m = 0) -------------
    Kb[0][lds_i] = *reinterpret_cast<const int4*>(khz + koff);
    __syncthreads();
    for (int kt = 0; kt <= ktmax; ++kt) {
        const int cur = kt & 1;
        const bool pf = (kt < ktmax);
        int4 kreg;
        if (pf)
            kreg = *reinterpret_cast<const int4*>(khz + (kt + 1) * 4096 + koff);

        f32x4 sacc[4];
#pragma unroll
        for (int n = 0; n < 4; ++n) sacc[n] = zf;
        __builtin_amdgcn_s_setprio(1);
#pragma unroll
        for (int eh = 0; eh < 2; ++eh) {
#pragma unroll
            for (int n = 0; n < 4; ++n) {
                const int kc = n * 16 + j;
                short8 kf = *reinterpret_cast<const short8*>(
                    &Kb[cur][kc * 8 + ((eh * 4 + g) ^ (j & 7))]);
                sacc[n] = mfma16(qf[eh], kf, sacc[n]);
            }
        }
        __builtin_amdgcn_s_setprio(0);

        if (kt >= 2 * qt) {
#pragma unroll
            for (int n = 0; n < 4; ++n) {
                const int col = kt * 64 + n * 16 + j;
#pragma unroll
                for (int r = 0; r < 4; ++r)
                    if (col > qr_base + r) sacc[n][r] = NEG_BIG;
            }
        }
#pragma unroll
        for (int r = 0; r < 4; ++r)
            lsum[r] += (exp2f(sacc[0][r]) + exp2f(sacc[1][r])) +
                       (exp2f(sacc[2][r]) + exp2f(sacc[3][r]));

        if (pf) Kb[cur ^ 1][lds_i] = kreg;
        __syncthreads();
    }

    // one-time cross-lane merge (16 lanes j share a q-row)
    float invl[4];
#pragma unroll
    for (int r = 0; r < 4; ++r) {
        float tt = lsum[r];
        tt += __shfl_xor(tt, 1);
        tt += __shfl_xor(tt, 2);
        tt += __shfl_xor(tt, 4);
        tt += __shfl_xor(tt, 8);
        invl[r] = 1.0f / tt;
    }

    // ------- phase 2: recompute + weights write + 1-deep pipelined PV ----
    f32x4 oacc[4];
#pragma unroll
    for (int n = 0; n < 4; ++n) oacc[n] = zf;

    Kb[0][lds_i] = *reinterpret_cast<const int4*>(khz + koff);
    Vb[0][lds_i] = *reinterpret_cast<const int4*>(vtz + voff);
    __syncthreads();
    int v_rd = 0;  // Vb slot holding tile kt
    for (int kt = 0; kt <= ktmax; ++kt) {
        const int kcur = kt & 1;
        const int pcur = kt & 1;          // Ps slot for tile kt
        const bool pf = (kt < ktmax);
        int v_wr = v_rd + 1; if (v_wr == 3) v_wr = 0;   // slot for tile kt+1
        int v_pv = v_rd - 1; if (v_pv < 0) v_pv = 2;    // slot of tile kt-1
        int4 kreg, vreg;
        if (pf) {
            kreg = *reinterpret_cast<const int4*>(khz + (kt + 1) * 4096 + koff);
            vreg = *reinterpret_cast<const int4*>(vtz + (kt + 1) * 64 + voff);
        }

        // QK^T(kt)
        f32x4 sacc[4];
#pragma unroll
        for (int n = 0; n < 4; ++n) sacc[n] = zf;
        __builtin_amdgcn_s_setprio(1);
#pragma unroll
        for (int eh = 0; eh < 2; ++eh) {
#pragma unroll
            for (int n = 0; n < 4; ++n) {
                const int kc = n * 16 + j;
                short8 kf = *reinterpret_cast<const short8*>(
                    &Kb[kcur][kc * 8 + ((eh * 4 + g) ^ (j & 7))]);
                sacc[n] = mfma16(qf[eh], kf, sacc[n]);
            }
        }

        // PV(kt-1): reads Ps[pcur^1] (committed last iter) and Vb[v_pv].
        // Independent of QK^T(kt) -> matrix pipe stays busy while the exp
        // VALU below crunches tile kt.
        if (kt > 0) {
#pragma unroll
            for (int ks = 0; ks < 2; ++ks) {
                short8 pa = *reinterpret_cast<const short8*>(
                    &Ps[pcur ^ 1][wv][j][ks * 32 + g * 8]);
#pragma unroll
                for (int n = 0; n < 4; ++n) {
                    const int e = n * 16 + j;
                    short8 vb = *reinterpret_cast<const short8*>(
                        &Vb[v_pv][e * 8 + ((ks * 4 + g) ^ (j & 7))]);
                    oacc[n] = mfma16(pa, vb, oacc[n]);
                }
            }
        }
        __builtin_amdgcn_s_setprio(0);

        if (kt >= 2 * qt) {
#pragma unroll
            for (int n = 0; n < 4; ++n) {
                const int col = kt * 64 + n * 16 + j;
#pragma unroll
                for (int r = 0; r < 4; ++r)
                    if (col > qr_base + r) sacc[n][r] = NEG_BIG;
            }
        }

#pragma unroll
        for (int n = 0; n < 4; ++n) {
#pragma unroll
            for (int r = 0; r < 4; ++r) {
                float p = exp2f(sacc[n][r]) * invl[r];
                wz[(size_t)(qr_base + r) * S_ + kt * 64 + n * 16 + j] = p;
                Ps[pcur][wv][g * 4 + r][n * 16 + j] = f2bf_fast(p);
            }
        }

        if (pf) {
            Kb[kcur ^ 1][lds_i] = kreg;
            Vb[v_wr][lds_i] = vreg;
        }
        __syncthreads();
        v_rd = v_wr;
    }

    // epilogue: PV for the final tile (ktmax)
    {
        const int p_last = ktmax & 1;
        int v_pv = v_rd - 1; if (v_pv < 0) v_pv = 2;  // slot of tile ktmax
        __builtin_amdgcn_s_setprio(1);
#pragma unroll
        for (int ks = 0; ks < 2; ++ks) {
            short8 pa = *reinterpret_cast<const short8*>(
                &Ps[p_last][wv][j][ks * 32 + g * 8]);
#pragma unroll
            for (int n = 0; n < 4; ++n) {
                const int e = n * 16 + j;
                short8 vb = *reinterpret_cast<const short8*>(
                    &Vb[v_pv][e * 8 + ((ks * 4 + g) ^ (j & 7))]);
                oacc[n] = mfma16(pa, vb, oacc[n]);
            }
        }
        __builtin_amdgcn_s_setprio(0);
    }

    // write attn bf16 in concat layout [b][s][h*64+e]
    {
        const int b = z >> 4, hh = z & 15;
#pragma unroll
        for (int n = 0; n < 4; ++n)
#pragma unroll
            for (int r = 0; r < 4; ++r)
                attnc[((size_t)(b * S_ + qr_base + r)) * D_ + hh * E_ +
                      n * 16 + j] = f2bf_fast(oacc[n][r]);
    }

    // zero-fill the fully-masked (upper-triangle) weight columns
    const int c0 = q0 + QBLK;
    const int w4 = (S_ - c0) >> 2;
    if (w4 > 0) {
        const float4 z4 = make_float4(0.f, 0.f, 0.f, 0.f);
        for (int row = 0; row < QBLK; ++row) {
            float4* rp =
                reinterpret_cast<float4*>(wz + (size_t)(q0 + row) * S_ + c0);
            for (int c = t; c < w4; c += 512) rp[c] = z4;
        }
    }
}

// ---------------------------------------------------------------------------
// 128x128-tile out-projection: attnc bf16 [4096][1024] x Wot bf16 [n][k]
// + bo -> out fp32 [4096][1024].  grid 256 (XCD-swizzled), block 512.
// ---------------------------------------------------------------------------
__global__ __launch_bounds__(512) void outproj_mfma_kernel(
    const ushort* __restrict__ A, const ushort* __restrict__ Wot,
    const float* __restrict__ bo, float* __restrict__ out) {
    const int bid = blockIdx.x;
    const int w = (bid & 7) * 32 + (bid >> 3);
    const int mt = w >> 3, nt = w & 7;
    const int gm0 = mt * 128, n0 = nt * 128;
    const int t = threadIdx.x;
    const int wv = t >> 6, l = t & 63, j = l & 15, g = l >> 4;
    const int wm = wv >> 2, wn = wv & 3;

    __shared__ int4 As[2][1024];
    __shared__ int4 Bs[2][1024];

    const f32x4 zf = {0.f, 0.f, 0.f, 0.f};
    f32x4 acc[4][2];
#pragma unroll
    for (int mm = 0; mm < 4; ++mm) { acc[mm][0] = zf; acc[mm][1] = zf; }

    const int rr0 = t >> 3, bb0 = t & 7;
    const int rr1 = (t + 512) >> 3, bb1 = t & 7;
    const int slot0 = rr0 * 8 + (bb0 ^ (rr0 & 7));
    const int slot1 = rr1 * 8 + (bb1 ^ (rr1 & 7));

    As[0][slot0] = *reinterpret_cast<const int4*>(A + (size_t)(gm0 + rr0) * D_ + bb0 * 8);
    Bs[0][slot0] = *reinterpret_cast<const int4*>(Wot + (size_t)(n0 + rr0) * D_ + bb0 * 8);
    As[0][slot1] = *reinterpret_cast<const int4*>(A + (size_t)(gm0 + rr1) * D_ + bb1 * 8);
    Bs[0][slot1] = *reinterpret_cast<const int4*>(Wot + (size_t)(n0 + rr1) * D_ + bb1 * 8);
    __syncthreads();

    for (int ks = 0; ks < 16; ++ks) {
        const int cur = ks & 1;
        const bool pf = (ks < 15);
        int4 ar0, br0, ar1, br1;
        if (pf) {
            const int k0n = (ks + 1) * 64;
            ar0 = *reinterpret_cast<const int4*>(A + (size_t)(gm0 + rr0) * D_ + k0n + bb0 * 8);
            br0 = *reinterpret_cast<const int4*>(Wot + (size_t)(n0 + rr0) * D_ + k0n + bb0 * 8);
            ar1 = *reinterpret_cast<const int4*>(A + (size_t)(gm0 + rr1) * D_ + k0n + bb1 * 8);
            br1 = *reinterpret_cast<const int4*>(Wot + (size_t)(n0 + rr1) * D_ + k0n + bb1 * 8);
        }

        __builtin_amdgcn_s_setprio(1);
#pragma unroll
        for (int eh = 0; eh < 2; ++eh) {
            short8 bfr[2];
#pragma unroll
            for (int nn = 0; nn < 2; ++nn) {
                int e = wn * 32 + nn * 16 + j;
                bfr[nn] = *reinterpret_cast<const short8*>(
                    &Bs[cur][e * 8 + ((eh * 4 + g) ^ (e & 7))]);
            }
#pragma unroll
            for (int mm = 0; mm < 4; ++mm) {
                int arow = wm * 64 + mm * 16 + j;
                short8 a = *reinterpret_cast<const short8*>(
                    &As[cur][arow * 8 + ((eh * 4 + g) ^ (arow & 7))]);
                acc[mm][0] = mfma16(a, bfr[0], acc[mm][0]);
                acc[mm][1] = mfma16(a, bfr[1], acc[mm][1]);
            }
        }
        __builtin_amdgcn_s_setprio(0);

        if (pf) {
            As[cur ^ 1][slot0] = ar0; Bs[cur ^ 1][slot0] = br0;
            As[cur ^ 1][slot1] = ar1; Bs[cur ^ 1][slot1] = br1;
        }
        __syncthreads();
    }

#pragma unroll
    for (int nn = 0; nn < 2; ++nn) {
        const int ncol = n0 + wn * 32 + nn * 16 + j;
        const float bvv = bo[ncol];
#pragma unroll
        for (int mm = 0; mm < 4; ++mm) {
            const int m = gm0 + wm * 64 + mm * 16 + g * 4;
#pragma unroll
            for (int r = 0; r < 4; ++r)
                out[(size_t)(m + r) * D_ + ncol] = acc[mm][nn][r] + bvv;
        }
    }
}

// ---------------------------------------------------------------------------
extern "C" void kernel_launch(void* const* d_in, const int* in_sizes, int n_in,
                              void* d_out, int out_size, void* d_ws,
                              size_t ws_size, hipStream_t stream) {
    const float* q = (const float*)d_in[0];
    const float* k = (const float*)d_in[1];
    const float* v = (const float*)d_in[2];
    const float* Wq = (const float*)d_in[3];
    const float* bq = (const float*)d_in[4];
    const float* Wk = (const float*)d_in[5];
    const float* bk = (const float*)d_in[6];
    const float* Wv = (const float*)d_in[7];
    const float* bv = (const float*)d_in[8];
    const float* Wo = (const float*)d_in[9];
    const float* bo = (const float*)d_in[10];

    float* out = (float*)d_out;                    // [B,S,D]
    float* wts = out + (size_t)B_ * S_ * D_;       // [B,H,S,S]

    const size_t NZ = (size_t)Z_ * S_ * E_;        // 4,194,304
    const size_t NW = (size_t)H_ * E_ * D_;        // 1,048,576
    ushort* qh = (ushort*)d_ws;                    // bf16 [z][s][64] (scaled)
    ushort* kh = qh + NZ;                          // bf16 [z][s][64]
    ushort* vt = kh + NZ;                          // bf16 [z][64][s]
    ushort* attnc = vt + NZ;                       // bf16 [4096][1024] concat
    ushort* Wqt = attnc + NZ;                      // bf16 [h][64][1024]
    ushort* Wkt = Wqt + NW;
    ushort* Wvt = Wkt + NW;
    ushort* Wot = Wvt + NW;                        // bf16 [1024][1024] ([n][k])

    // bf16 copies of q/k/v staged in the (not-yet-written) wts region of
    // d_out; dead before attn_fused writes wts.
    ushort* xq = (ushort*)wts;
    ushort* xk = xq + NZ;
    ushort* xv = xk + NZ;

    const float QSCALE = 0.125f * 1.44269504088896340736f;  // 1/8 * log2(e)
    const int n4 = (int)(NZ / 4);

    dim3 b256(256), b512(512);
    cvt3_kernel<<<dim3(4096, 3), b256, 0, stream>>>(q, k, v, xq, xk, xv, n4);
    wtrans3_kernel<<<dim3(32, 2, 48), b256, 0, stream>>>(Wq, Wk, Wv, Wqt, Wkt,
                                                         Wvt);
    wtrans_kernel<<<dim3(32, 32, 1), b256, 0, stream>>>(Wo, Wot, D_, D_);
    proj3_mfma_kernel<<<dim3(768), b512, 0, stream>>>(
        xq, xk, xv, Wqt, Wkt, Wvt, bq, bk, bv, qh, kh, vt, QSCALE);
    attn_fused_kernel<<<dim3(512), b512, 0, stream>>>(qh, kh, vt, wts, attnc);
    outproj_mfma_kernel<<<dim3(256), b512, 0, stream>>>(attnc, Wot, bo, out);
}